// Round 19
// baseline (62.860 us; speedup 1.0000x reference)
//
#include <hip/hip_runtime.h>

#define S_LEN 4096
#define D_MODEL 256
#define NH 4
#define DH 64
#define CSC 0.18033688011112042f   // log2(e) / sqrt(64)
#define FRAG 520                   // ushorts per fragment slot (512 + 8 pad)

typedef __attribute__((ext_vector_type(8))) short bf16x8;
typedef __attribute__((ext_vector_type(8))) unsigned short u16x8;
typedef __attribute__((ext_vector_type(4))) float f32x4;
typedef __attribute__((ext_vector_type(16))) float f32x16;
typedef __attribute__((ext_vector_type(2))) unsigned int u32x2;
typedef __attribute__((ext_vector_type(4))) unsigned int u32x4;

#define MFMA16(a, b, c) __builtin_amdgcn_mfma_f32_16x16x32_bf16((a), (b), (c), 0, 0, 0)
#define MFMA32(a, b, c) __builtin_amdgcn_mfma_f32_32x32x16_bf16((a), (b), (c), 0, 0, 0)

static __device__ __forceinline__ unsigned short f2bf(float f) {
  unsigned int u = __float_as_uint(f);
  u += 0x7fffu + ((u >> 16) & 1u);   // RTNE
  return (unsigned short)(u >> 16);
}

static __device__ __forceinline__ unsigned int cvtpk(float lo, float hi) {
  unsigned int r;
  asm("v_cvt_pk_bf16_f32 %0, %1, %2" : "=v"(r) : "v"(lo), "v"(hi));
  return r;   // lo -> [15:0], hi -> [31:16], RTNE
}

static __device__ __forceinline__ u16x8 cvt8(float4 a, float4 b) {
  u16x8 v;
  v[0] = f2bf(a.x); v[1] = f2bf(a.y); v[2] = f2bf(a.z); v[3] = f2bf(a.w);
  v[4] = f2bf(b.x); v[5] = f2bf(b.y); v[6] = f2bf(b.z); v[7] = f2bf(b.w);
  return v;
}

// Half of R14's pack_pb: one 32-row S^T tile (f32 C-layout) -> 2 bf16 B-frags.
static __device__ __forceinline__ void pack_half(const f32x16& s, bf16x8* pb) {
  unsigned int u[8];
#pragma unroll
  for (int gg = 0; gg < 4; ++gg) {
    u[gg * 2 + 0] = cvtpk(s[4 * gg + 0], s[4 * gg + 1]);
    u[gg * 2 + 1] = cvtpk(s[4 * gg + 2], s[4 * gg + 3]);
  }
#pragma unroll
  for (int S = 0; S < 2; ++S) {
    u32x2 w0 = __builtin_amdgcn_permlane32_swap(u[4 * S + 0], u[4 * S + 2], false, false);
    u32x2 w1 = __builtin_amdgcn_permlane32_swap(u[4 * S + 1], u[4 * S + 3], false, false);
    u32x4 t0; t0[0] = w0[0]; t0[1] = w1[0]; t0[2] = w0[1]; t0[3] = w1[1];
    pb[S] = __builtin_bit_cast(bf16x8, t0);
  }
}

// ---------------------------------------------------------------------------
// Kernel 0: convert W{q,k,v} to bf16 in MFMA-B-fragment order (16x16x32).
// ---------------------------------------------------------------------------
__global__ __launch_bounds__(256) void prep(
    const float* __restrict__ Wq, const float* __restrict__ Wk,
    const float* __restrict__ Wv, unsigned short* __restrict__ Wb)
{
  const int gid = blockIdx.x * 256 + threadIdx.x;
  const int l   = gid & 63;
  const int f   = gid >> 6;
  const int kk  = f & 7;
  const int ctn = f >> 3;
  const int ct  = ctn & 3, nt = ctn >> 2;
  const int pj  = nt >> 2, h = nt & 3;
  const float* Wsel = (pj == 0) ? Wq : (pj == 1) ? Wk : Wv;
  const float* src =
      Wsel + (size_t)(h * 64 + ct * 16 + (l & 15)) * D_MODEL + kk * 32 + (l >> 4) * 8;
  float4 a = *(const float4*)src;
  float4 b = *(const float4*)(src + 4);
  *(u16x8*)(Wb + (size_t)gid * 8) = cvt8(a, b);
}

// ---------------------------------------------------------------------------
// Kernel 1: QKV projection. grid = 1024 (256 m-tiles x 4 nt-triplets) ->
// 4 blocks/CU = 4 waves/SIMD (was 2): halves exposed latency of the 12
// serial barrier phases. Q pre-scaled by CSC; V transposed Vt[bh][d][s].
// ---------------------------------------------------------------------------
__global__ __launch_bounds__(256) void qkv_proj(
    const float* __restrict__ x, const unsigned short* __restrict__ Wb,
    const float* __restrict__ bq, const float* __restrict__ bk,
    const float* __restrict__ bv,
    unsigned short* __restrict__ Qh, unsigned short* __restrict__ Kh,
    unsigned short* __restrict__ Vt)
{
  __shared__ unsigned short xs[32][264];
  __shared__ float tbuf[32][68];          // block transpose buffer

  const int tid  = threadIdx.x;
  const int lane = tid & 63;
  const int w    = tid >> 6;
  const int r16  = lane & 15;
  const int hi   = lane >> 4;
  const int m0   = (blockIdx.x >> 2) * 32;
  const int ntB  = (blockIdx.x & 3) * 3;

  {  // stage x tile: 32 rows x 256 f32 -> bf16
    const int r  = tid >> 3;
    const int c0 = (tid & 7) * 32;
    const float* xp = x + (size_t)(m0 + r) * D_MODEL + c0;
#pragma unroll
    for (int i = 0; i < 32; i += 8) {
      float4 a = *(const float4*)(xp + i);
      float4 b = *(const float4*)(xp + i + 4);
      *(u16x8*)&xs[r][c0 + i] = cvt8(a, b);
    }
  }
  __syncthreads();

  const int bb = m0 >> 12;
  const int s_base = m0 & 4095;

  for (int t = 0; t < 3; ++t) {
    const int nt = ntB + t, pj = nt >> 2, h = nt & 3;
    f32x4 acc[2] = {};
    const size_t fb = (size_t)(nt * 4 + w) * 8;
#pragma unroll
    for (int kk = 0; kk < 8; ++kk) {
      bf16x8 bw = *(const bf16x8*)(Wb + (fb + kk) * 512 + lane * 8);
#pragma unroll
      for (int rt = 0; rt < 2; ++rt) {
        bf16x8 af = *(const bf16x8*)&xs[rt * 16 + r16][kk * 32 + hi * 8];
        acc[rt] = MFMA16(af, bw, acc[rt]);
      }
    }
    const float* bsel = (pj == 0) ? bq : (pj == 1) ? bk : bv;
    const float bias = bsel[h * 64 + w * 16 + r16];
    const float scl  = (pj == 0) ? CSC : 1.0f;

    // scatter into f32 transpose buffer [s_local][e_local]
#pragma unroll
    for (int rt = 0; rt < 2; ++rt)
#pragma unroll
      for (int j = 0; j < 4; ++j)
        tbuf[rt * 16 + hi * 4 + j][w * 16 + r16] = (acc[rt][j] + bias) * scl;
    __syncthreads();

    if (pj < 2) {   // coalesced 128B-row stores: thread -> (s_l, 8 cols)
      const int s_l = tid >> 3, c0 = (tid & 7) * 8;
      float4 a = *(const float4*)&tbuf[s_l][c0];
      float4 b = *(const float4*)&tbuf[s_l][c0 + 4];
      unsigned short* dst = ((pj == 0) ? Qh : Kh) +
          ((size_t)(bb * NH + h) * S_LEN + s_base + s_l) * DH + c0;
      *(u16x8*)dst = cvt8(a, b);
    } else {        // V transposed: thread -> (d_l, 8 s)
      const int d_l = tid & 63, sblk = (tid >> 6) * 8;
      u16x8 vv;
#pragma unroll
      for (int e = 0; e < 8; ++e) vv[e] = f2bf(tbuf[sblk + e][d_l]);
      unsigned short* dst = Vt +
          ((size_t)(bb * NH + h) * DH + d_l) * S_LEN + s_base + sblk;
      *(u16x8*)dst = vv;
    }
    __syncthreads();
  }
}

// ---------------------------------------------------------------------------
// Kernel 2: attention. R14 structure + in-chunk software pipeline:
// s0 (K-frags 0,2,4,6; t 0-31) and s1 (frags 1,3,5,7) are independent
// through exp2/pack, and PV k-slots 0-1 need only pb[0..1] (from s0).
// Schedule: QK(s0) -> QK(s1) issue -> exp2(s0) [overlaps s1 MFMAs] ->
// pack(s0) -> PV1 -> STAGE -> exp2(s1) [overlaps PV1 MFMAs] -> pack(s1)
// -> PV2. Same ops/barriers/liveness as R14 (passing baseline), only
// reordered. grid = 256, 1024 thr = 16 waves (4 KV-groups x 4 q-waves),
// frag-linear LDS, named-scalar staging, no-max softmax, combine 4->2->1.
// ---------------------------------------------------------------------------
__global__ __launch_bounds__(1024) void attn(
    const unsigned short* __restrict__ Qh,
    const unsigned short* __restrict__ Kh,
    const unsigned short* __restrict__ Vt,
    float* __restrict__ out)
{
  __shared__ unsigned short KV[2][2][4][8 * FRAG];  // [parity][K/V][grp][slots]

  const int tid = threadIdx.x;
  const int ln  = tid & 63;
  const int wv  = tid >> 6;       // 0..15
  const int g   = wv >> 2;        // KV group 0..3
  const int wq  = wv & 3;         // q sub-tile
  const int r32 = ln & 31;
  const int h   = ln >> 5;

  const int bid = blockIdx.x;
  const int bh  = bid & 7;                 // XCD-local bh
  const int q0  = (bid >> 3) * 128;

  const unsigned short* Qb = Qh + (size_t)bh * S_LEN * DH;
  const unsigned short* Kb = Kh + (size_t)bh * S_LEN * DH;
  const unsigned short* Vb = Vt + (size_t)bh * DH * S_LEN;

  // Q as B-operand of swapped QK: lane holds Q[q=r32][d = s*16 + h*8 + j]
  const int q = q0 + wq * 32 + r32;
  bf16x8 qf[4];
#pragma unroll
  for (int s = 0; s < 4; ++s)
    qf[s] = *(const bf16x8*)(Qb + (size_t)q * DH + s * 16 + h * 8);

  f32x16 o0 = {}, o1 = {};     // o^T: col=q, rows=d (two 32-d tiles)
  float l_run = 0.f;

  // ---- staging (named scalars only; no arrays -> no scratch) ----
  const int u  = tid & 255;
  const int gs = tid >> 8;         // staging group == own wave's g
  const int sr = u >> 2;           // row 0..63 (t for K, d for V^T)
  const int sc = (u & 3) * 16;     // ushort col
  // frag-scatter offsets (verified bijection, R8-R18 absmax-passed)
  const int f0   = (sc >> 4) * 2 + (sr >> 5);
  const int offA = f0 * FRAG + (sr & 31) * 8;
  const int offB = offA + 256;

  uint4 kA, kB, vA, vB;
#define LOAD_CHUNK(c)                                                          \
  { const unsigned short* kp = Kb + ((size_t)(c) * 64 + sr) * DH + sc;         \
    kA = *(const uint4*)kp;  kB = *(const uint4*)(kp + 8);                     \
    const unsigned short* vp = Vb + (size_t)sr * S_LEN + (c) * 64 + sc;        \
    vA = *(const uint4*)vp;  vB = *(const uint4*)(vp + 8); }
#define STAGE(par)                                                             \
  { unsigned short* kd = &KV[par][0][gs][0];                                   \
    *(uint4*)(kd + offA) = kA;  *(uint4*)(kd + offB) = kB;                     \
    unsigned short* vd = &KV[par][1][gs][0];                                   \
    *(uint4*)(vd + offA) = vA;  *(uint4*)(vd + offB) = vB; }

  LOAD_CHUNK(gs);
  STAGE(0);
  LOAD_CHUNK(4 + gs);

  for (int it = 0; it < 16; ++it) {
    __syncthreads();   // parity-(it&1) writes visible; prior same-parity reads done
    const unsigned short* Kc = &KV[it & 1][0][g][0];
    const unsigned short* Vc = &KV[it & 1][1][g][0];
    const int lb = ln * 8;

    // ---- QK s0: K frags 0,2,4,6 (t 0-31) ----
    f32x16 s0 = {};
    __builtin_amdgcn_s_setprio(1);
#pragma unroll
    for (int s = 0; s < 4; ++s) {
      bf16x8 a0 = *(const bf16x8*)(Kc + lb + (2 * s + 0) * FRAG);
      s0 = MFMA32(a0, qf[s], s0);
    }
    __builtin_amdgcn_s_setprio(0);

    // ---- QK s1 issue: frags 1,3,5,7 (t 32-63); MFMAs fill matrix pipe ----
    f32x16 s1 = {};
    __builtin_amdgcn_s_setprio(1);
#pragma unroll
    for (int s = 0; s < 4; ++s) {
      bf16x8 a1 = *(const bf16x8*)(Kc + lb + (2 * s + 1) * FRAG);
      s1 = MFMA32(a1, qf[s], s1);
    }
    __builtin_amdgcn_s_setprio(0);

    // ---- exp2(s0) + sum: VALU overlaps s1's MFMAs ----
    {
      float pa = 0.f, pbs = 0.f;
#pragma unroll
      for (int i = 0; i < 16; i += 2) {
        s0[i]     = __builtin_amdgcn_exp2f(s0[i]);      pa  += s0[i];
        s0[i + 1] = __builtin_amdgcn_exp2f(s0[i + 1]);  pbs += s0[i + 1];
      }
      l_run += pa + pbs;
    }
    bf16x8 p01[2];
    pack_half(s0, p01);

    // ---- PV part1: V frags 0-3 (k-slots 0,1 <- s0 only) ----
    __builtin_amdgcn_s_setprio(1);
#pragma unroll
    for (int s = 0; s < 2; ++s) {
      bf16x8 b0 = *(const bf16x8*)(Vc + lb + (2 * s + 0) * FRAG);
      bf16x8 b1 = *(const bf16x8*)(Vc + lb + (2 * s + 1) * FRAG);
      o0 = MFMA32(b0, p01[s], o0);
      o1 = MFMA32(b1, p01[s], o1);
    }
    __builtin_amdgcn_s_setprio(0);

    // ---- STAGE + prefetch: DS writes drain under exp2(s1) VALU ----
    if (it < 15) {
      STAGE((it + 1) & 1);
      int c = 4 * (it + 2) + gs;  if (c > 63) c = 63;   // prefetch for it+2
      LOAD_CHUNK(c);
    }

    // ---- exp2(s1) + sum: overlaps PV1 MFMAs ----
    {
      float pa = 0.f, pbs = 0.f;
#pragma unroll
      for (int i = 0; i < 16; i += 2) {
        s1[i]     = __builtin_amdgcn_exp2f(s1[i]);      pa  += s1[i];
        s1[i + 1] = __builtin_amdgcn_exp2f(s1[i + 1]);  pbs += s1[i + 1];
      }
      l_run += pa + pbs;
    }
    bf16x8 p23[2];
    pack_half(s1, p23);

    // ---- PV part2: V frags 4-7 (k-slots 2,3 <- s1) ----
    __builtin_amdgcn_s_setprio(1);
#pragma unroll
    for (int s = 0; s < 2; ++s) {
      bf16x8 b0 = *(const bf16x8*)(Vc + lb + (4 + 2 * s) * FRAG);
      bf16x8 b1 = *(const bf16x8*)(Vc + lb + (5 + 2 * s) * FRAG);
      o0 = MFMA32(b0, p23[s], o0);
      o1 = MFMA32(b1, p23[s], o1);
    }
    __builtin_amdgcn_s_setprio(0);
  }

  // ---- KV-split combine: 4 -> 2 -> 1 (exact: partials additive) ----
  __syncthreads();                            // last computes done
  float* cb = (float*)&KV[0][0][0][0];        // scratch; rounds use <70KB
  const int cbase = wq * 64 + ln;             // 0..255

  // round 1: groups 2,3 publish; groups 0,1 absorb
  if (g >= 2) {
    const int base = ((g - 2) * 256 + cbase) * 33;
#pragma unroll
    for (int i = 0; i < 16; ++i) { cb[base + i] = o0[i]; cb[base + 16 + i] = o1[i]; }
    cb[base + 32] = l_run;
  }
  __syncthreads();
  if (g < 2) {
    const int base = (g * 256 + cbase) * 33;
#pragma unroll
    for (int i = 0; i < 16; ++i) { o0[i] += cb[base + i]; o1[i] += cb[base + 16 + i]; }
    l_run += cb[base + 32];
  }
  __syncthreads();
  // round 2: group 1 publishes; group 0 absorbs
  if (g == 1) {
    const int base = cbase * 33;
#pragma unroll
    for (int i = 0; i < 16; ++i) { cb[base + i] = o0[i]; cb[base + 16 + i] = o1[i]; }
    cb[base + 32] = l_run;
  }
  __syncthreads();
  if (g == 0) {
    const int base = cbase * 33;
#pragma unroll
    for (int i = 0; i < 16; ++i) { o0[i] += cb[base + i]; o1[i] += cb[base + 16 + i]; }
    l_run += cb[base + 32];

    // ---- epilogue: l across h-halves, normalize, store ----
    const float lt  = l_run + __shfl_xor(l_run, 32);
    const float inv = 1.f / lt;
    const int bb = bh >> 2, hd = bh & 3;
    float* op = out + ((size_t)(bb * S_LEN + q)) * D_MODEL + hd * DH;
#pragma unroll
    for (int gg = 0; gg < 4; ++gg) {
      float4 v0, v1;
      v0.x = o0[4 * gg + 0] * inv;  v0.y = o0[4 * gg + 1] * inv;
      v0.z = o0[4 * gg + 2] * inv;  v0.w = o0[4 * gg + 3] * inv;
      *(float4*)(op + 8 * gg + 4 * h) = v0;
      v1.x = o1[4 * gg + 0] * inv;  v1.y = o1[4 * gg + 1] * inv;
      v1.z = o1[4 * gg + 2] * inv;  v1.w = o1[4 * gg + 3] * inv;
      *(float4*)(op + 32 + 8 * gg + 4 * h) = v1;
    }
  }
}

// ---------------------------------------------------------------------------
extern "C" void kernel_launch(void* const* d_in, const int* in_sizes, int n_in,
                              void* d_out, int out_size, void* d_ws, size_t ws_size,
                              hipStream_t stream) {
  const float* x  = (const float*)d_in[0];
  const float* Wq = (const float*)d_in[1];
  const float* bq = (const float*)d_in[2];
  const float* Wk = (const float*)d_in[3];
  const float* bk = (const float*)d_in[4];
  const float* Wv = (const float*)d_in[5];
  const float* bv = (const float*)d_in[6];
  float* out = (float*)d_out;

  const size_t per = (size_t)2 * NH * S_LEN * DH;       // 2M bf16 elems each
  if (ws_size < 3 * per * sizeof(unsigned short)) return;
  unsigned short* Qh = (unsigned short*)d_ws;
  unsigned short* Kh = Qh + per;
  unsigned short* Vt = Kh + per;
  unsigned short* Wb = (unsigned short*)d_out;   // scratch; attn overwrites out

  prep<<<96, 256, 0, stream>>>(Wq, Wk, Wv, Wb);
  qkv_proj<<<1024, 256, 0, stream>>>(x, Wb, bq, bk, bv, Qh, Kh, Vt);
  attn<<<256, 1024, 0, stream>>>(Qh, Kh, Vt, out);
}

// Round 20
// 61.401 us; speedup vs baseline: 1.0238x; 1.0238x over previous
//
#include <hip/hip_runtime.h>

#define S_LEN 4096
#define D_MODEL 256
#define NH 4
#define DH 64
#define CSC 0.18033688011112042f   // log2(e) / sqrt(64)
#define FRAG 520                   // ushorts per fragment slot (512 + 8 pad)

typedef __attribute__((ext_vector_type(8))) short bf16x8;
typedef __attribute__((ext_vector_type(8))) unsigned short u16x8;
typedef __attribute__((ext_vector_type(4))) float f32x4;
typedef __attribute__((ext_vector_type(16))) float f32x16;
typedef __attribute__((ext_vector_type(2))) unsigned int u32x2;
typedef __attribute__((ext_vector_type(4))) unsigned int u32x4;

#define MFMA16(a, b, c) __builtin_amdgcn_mfma_f32_16x16x32_bf16((a), (b), (c), 0, 0, 0)
#define MFMA32(a, b, c) __builtin_amdgcn_mfma_f32_32x32x16_bf16((a), (b), (c), 0, 0, 0)

static __device__ __forceinline__ unsigned short f2bf(float f) {
  unsigned int u = __float_as_uint(f);
  u += 0x7fffu + ((u >> 16) & 1u);   // RTNE
  return (unsigned short)(u >> 16);
}

static __device__ __forceinline__ unsigned int cvtpk(float lo, float hi) {
  unsigned int r;
  asm("v_cvt_pk_bf16_f32 %0, %1, %2" : "=v"(r) : "v"(lo), "v"(hi));
  return r;   // lo -> [15:0], hi -> [31:16], RTNE
}

static __device__ __forceinline__ u16x8 cvt8(float4 a, float4 b) {
  u16x8 v;
  v[0] = f2bf(a.x); v[1] = f2bf(a.y); v[2] = f2bf(a.z); v[3] = f2bf(a.w);
  v[4] = f2bf(b.x); v[5] = f2bf(b.y); v[6] = f2bf(b.z); v[7] = f2bf(b.w);
  return v;
}

// P(f32 C-layout, two 32-row t-tiles) -> 4 bf16 B-operand fragments
static __device__ __forceinline__ void pack_pb(const f32x16& s0, const f32x16& s1,
                                               bf16x8* pb) {
  unsigned int u0[8], u1[8];
#pragma unroll
  for (int gg = 0; gg < 4; ++gg) {
    u0[gg * 2 + 0] = cvtpk(s0[4 * gg + 0], s0[4 * gg + 1]);
    u0[gg * 2 + 1] = cvtpk(s0[4 * gg + 2], s0[4 * gg + 3]);
    u1[gg * 2 + 0] = cvtpk(s1[4 * gg + 0], s1[4 * gg + 1]);
    u1[gg * 2 + 1] = cvtpk(s1[4 * gg + 2], s1[4 * gg + 3]);
  }
#pragma unroll
  for (int S = 0; S < 2; ++S) {
    u32x2 w0 = __builtin_amdgcn_permlane32_swap(u0[4 * S + 0], u0[4 * S + 2], false, false);
    u32x2 w1 = __builtin_amdgcn_permlane32_swap(u0[4 * S + 1], u0[4 * S + 3], false, false);
    u32x4 t0; t0[0] = w0[0]; t0[1] = w1[0]; t0[2] = w0[1]; t0[3] = w1[1];
    pb[S] = __builtin_bit_cast(bf16x8, t0);
    u32x2 w2 = __builtin_amdgcn_permlane32_swap(u1[4 * S + 0], u1[4 * S + 2], false, false);
    u32x2 w3 = __builtin_amdgcn_permlane32_swap(u1[4 * S + 1], u1[4 * S + 3], false, false);
    u32x4 t1; t1[0] = w2[0]; t1[1] = w3[0]; t1[2] = w2[1]; t1[3] = w3[1];
    pb[2 + S] = __builtin_bit_cast(bf16x8, t1);
  }
}

// ---------------------------------------------------------------------------
// Kernel 0: convert W{q,k,v} to bf16 in MFMA-B-fragment order (16x16x32).
// ---------------------------------------------------------------------------
__global__ __launch_bounds__(256) void prep(
    const float* __restrict__ Wq, const float* __restrict__ Wk,
    const float* __restrict__ Wv, unsigned short* __restrict__ Wb)
{
  const int gid = blockIdx.x * 256 + threadIdx.x;
  const int l   = gid & 63;
  const int f   = gid >> 6;
  const int kk  = f & 7;
  const int ctn = f >> 3;
  const int ct  = ctn & 3, nt = ctn >> 2;
  const int pj  = nt >> 2, h = nt & 3;
  const float* Wsel = (pj == 0) ? Wq : (pj == 1) ? Wk : Wv;
  const float* src =
      Wsel + (size_t)(h * 64 + ct * 16 + (l & 15)) * D_MODEL + kk * 32 + (l >> 4) * 8;
  float4 a = *(const float4*)src;
  float4 b = *(const float4*)(src + 4);
  *(u16x8*)(Wb + (size_t)gid * 8) = cvt8(a, b);
}

// ---------------------------------------------------------------------------
// Kernel 1: QKV projection. grid = 1024 (256 m-tiles x 4 nt-triplets) ->
// 4 blocks/CU = 4 waves/SIMD (R19-measured: ~1us better than grid 512).
// Q pre-scaled by CSC; V transposed Vt[bh][d][s].
// ---------------------------------------------------------------------------
__global__ __launch_bounds__(256) void qkv_proj(
    const float* __restrict__ x, const unsigned short* __restrict__ Wb,
    const float* __restrict__ bq, const float* __restrict__ bk,
    const float* __restrict__ bv,
    unsigned short* __restrict__ Qh, unsigned short* __restrict__ Kh,
    unsigned short* __restrict__ Vt)
{
  __shared__ unsigned short xs[32][264];
  __shared__ float tbuf[32][68];          // block transpose buffer

  const int tid  = threadIdx.x;
  const int lane = tid & 63;
  const int w    = tid >> 6;
  const int r16  = lane & 15;
  const int hi   = lane >> 4;
  const int m0   = (blockIdx.x >> 2) * 32;
  const int ntB  = (blockIdx.x & 3) * 3;

  {  // stage x tile: 32 rows x 256 f32 -> bf16
    const int r  = tid >> 3;
    const int c0 = (tid & 7) * 32;
    const float* xp = x + (size_t)(m0 + r) * D_MODEL + c0;
#pragma unroll
    for (int i = 0; i < 32; i += 8) {
      float4 a = *(const float4*)(xp + i);
      float4 b = *(const float4*)(xp + i + 4);
      *(u16x8*)&xs[r][c0 + i] = cvt8(a, b);
    }
  }
  __syncthreads();

  const int bb = m0 >> 12;
  const int s_base = m0 & 4095;

  for (int t = 0; t < 3; ++t) {
    const int nt = ntB + t, pj = nt >> 2, h = nt & 3;
    f32x4 acc[2] = {};
    const size_t fb = (size_t)(nt * 4 + w) * 8;
#pragma unroll
    for (int kk = 0; kk < 8; ++kk) {
      bf16x8 bw = *(const bf16x8*)(Wb + (fb + kk) * 512 + lane * 8);
#pragma unroll
      for (int rt = 0; rt < 2; ++rt) {
        bf16x8 af = *(const bf16x8*)&xs[rt * 16 + r16][kk * 32 + hi * 8];
        acc[rt] = MFMA16(af, bw, acc[rt]);
      }
    }
    const float* bsel = (pj == 0) ? bq : (pj == 1) ? bk : bv;
    const float bias = bsel[h * 64 + w * 16 + r16];
    const float scl  = (pj == 0) ? CSC : 1.0f;

    // scatter into f32 transpose buffer [s_local][e_local]
#pragma unroll
    for (int rt = 0; rt < 2; ++rt)
#pragma unroll
      for (int j = 0; j < 4; ++j)
        tbuf[rt * 16 + hi * 4 + j][w * 16 + r16] = (acc[rt][j] + bias) * scl;
    __syncthreads();

    if (pj < 2) {   // coalesced 128B-row stores: thread -> (s_l, 8 cols)
      const int s_l = tid >> 3, c0 = (tid & 7) * 8;
      float4 a = *(const float4*)&tbuf[s_l][c0];
      float4 b = *(const float4*)&tbuf[s_l][c0 + 4];
      unsigned short* dst = ((pj == 0) ? Qh : Kh) +
          ((size_t)(bb * NH + h) * S_LEN + s_base + s_l) * DH + c0;
      *(u16x8*)dst = cvt8(a, b);
    } else {        // V transposed: thread -> (d_l, 8 s)
      const int d_l = tid & 63, sblk = (tid >> 6) * 8;
      u16x8 vv;
#pragma unroll
      for (int e = 0; e < 8; ++e) vv[e] = f2bf(tbuf[sblk + e][d_l]);
      unsigned short* dst = Vt +
          ((size_t)(bb * NH + h) * DH + d_l) * S_LEN + s_base + sblk;
      *(u16x8*)dst = vv;
    }
    __syncthreads();
  }
}

// ---------------------------------------------------------------------------
// Kernel 2: attention. EXACT R18/R14 loop (measured-passing 41.8us twice).
// DS-queue-aware ordering: K ds_reads (QK) issue FIRST after the barrier;
// STAGE ds_writes land during the exp2 VALU phase; V ds_reads follow pack.
// Softmax sum uses 4 accumulators. grid = 256 (bh = bid&7 per XCD; 32
// q-tiles of 128), 1024 thr = 16 waves (4 KV-groups x 4 q-waves),
// frag-linear LDS (conflict-free), named-scalar staging (no scratch),
// no-max softmax, combine 4->2->1.
// Retired attempts on this structure: R17 V-reg-prefetch (absmax fail,
// lgkmcnt window overflow); R19 manual in-chunk pipeline (-1.8us, reduced
// compiler scheduling freedom). DS pipe ~60% busy is the remaining wall;
// only structural fix is Q=64/wave (spilled in R8/R9).
// ---------------------------------------------------------------------------
__global__ __launch_bounds__(1024) void attn(
    const unsigned short* __restrict__ Qh,
    const unsigned short* __restrict__ Kh,
    const unsigned short* __restrict__ Vt,
    float* __restrict__ out)
{
  __shared__ unsigned short KV[2][2][4][8 * FRAG];  // [parity][K/V][grp][slots]

  const int tid = threadIdx.x;
  const int ln  = tid & 63;
  const int wv  = tid >> 6;       // 0..15
  const int g   = wv >> 2;        // KV group 0..3
  const int wq  = wv & 3;         // q sub-tile
  const int r32 = ln & 31;
  const int h   = ln >> 5;

  const int bid = blockIdx.x;
  const int bh  = bid & 7;                 // XCD-local bh
  const int q0  = (bid >> 3) * 128;

  const unsigned short* Qb = Qh + (size_t)bh * S_LEN * DH;
  const unsigned short* Kb = Kh + (size_t)bh * S_LEN * DH;
  const unsigned short* Vb = Vt + (size_t)bh * DH * S_LEN;

  // Q as B-operand of swapped QK: lane holds Q[q=r32][d = s*16 + h*8 + j]
  const int q = q0 + wq * 32 + r32;
  bf16x8 qf[4];
#pragma unroll
  for (int s = 0; s < 4; ++s)
    qf[s] = *(const bf16x8*)(Qb + (size_t)q * DH + s * 16 + h * 8);

  f32x16 o0 = {}, o1 = {};     // o^T: col=q, rows=d (two 32-d tiles)
  float l_run = 0.f;

  // ---- staging (named scalars only; no arrays -> no scratch) ----
  const int u  = tid & 255;
  const int gs = tid >> 8;         // staging group == own wave's g
  const int sr = u >> 2;           // row 0..63 (t for K, d for V^T)
  const int sc = (u & 3) * 16;     // ushort col
  // frag-scatter offsets (verified bijection, R8-R18 absmax-passed)
  const int f0   = (sc >> 4) * 2 + (sr >> 5);
  const int offA = f0 * FRAG + (sr & 31) * 8;
  const int offB = offA + 256;

  uint4 kA, kB, vA, vB;
#define LOAD_CHUNK(c)                                                          \
  { const unsigned short* kp = Kb + ((size_t)(c) * 64 + sr) * DH + sc;         \
    kA = *(const uint4*)kp;  kB = *(const uint4*)(kp + 8);                     \
    const unsigned short* vp = Vb + (size_t)sr * S_LEN + (c) * 64 + sc;        \
    vA = *(const uint4*)vp;  vB = *(const uint4*)(vp + 8); }
#define STAGE(par)                                                             \
  { unsigned short* kd = &KV[par][0][gs][0];                                   \
    *(uint4*)(kd + offA) = kA;  *(uint4*)(kd + offB) = kB;                     \
    unsigned short* vd = &KV[par][1][gs][0];                                   \
    *(uint4*)(vd + offA) = vA;  *(uint4*)(vd + offB) = vB; }

  LOAD_CHUNK(gs);
  STAGE(0);
  LOAD_CHUNK(4 + gs);

  for (int it = 0; it < 16; ++it) {
    __syncthreads();   // parity-(it&1) writes visible; prior same-parity reads done
    const unsigned short* Kc = &KV[it & 1][0][g][0];
    const unsigned short* Vc = &KV[it & 1][1][g][0];
    const int lb = ln * 8;

    // ---- QK^T first: K ds_reads hit an empty DS queue ----
    f32x16 s0 = {}, s1 = {};
    __builtin_amdgcn_s_setprio(1);
#pragma unroll
    for (int s = 0; s < 4; ++s) {
      bf16x8 a0 = *(const bf16x8*)(Kc + lb + (2 * s + 0) * FRAG);
      bf16x8 a1 = *(const bf16x8*)(Kc + lb + (2 * s + 1) * FRAG);
      s0 = MFMA32(a0, qf[s], s0);
      s1 = MFMA32(a1, qf[s], s1);
    }
    __builtin_amdgcn_s_setprio(0);

    // ---- P = exp2(S^T), 4-way tree sum (8-deep chains) ----
    float pa = 0.f, pbs = 0.f, pc = 0.f, pd = 0.f;
#pragma unroll
    for (int i = 0; i < 16; i += 2) {
      s0[i]     = __builtin_amdgcn_exp2f(s0[i]);      pa  += s0[i];
      s0[i + 1] = __builtin_amdgcn_exp2f(s0[i + 1]);  pbs += s0[i + 1];
      s1[i]     = __builtin_amdgcn_exp2f(s1[i]);      pc  += s1[i];
      s1[i + 1] = __builtin_amdgcn_exp2f(s1[i + 1]);  pd  += s1[i + 1];
    }
    l_run += (pa + pbs) + (pc + pd);

    // ---- STAGE ds_writes land during the VALU phase (DS pipe idle) ----
    if (it < 15) {
      STAGE((it + 1) & 1);
      int c = 4 * (it + 2) + gs;  if (c > 63) c = 63;   // prefetch for it+2
      LOAD_CHUNK(c);
    }

    // ---- P(f32 C-layout) -> bf16 B-operand frags ----
    bf16x8 pb[4];
    pack_pb(s0, s1, pb);

    // ---- PV (swapped): o^T[d][q] += V^T[d][t] * P^T[t][q] ----
    __builtin_amdgcn_s_setprio(1);
#pragma unroll
    for (int s = 0; s < 4; ++s) {
      bf16x8 b0 = *(const bf16x8*)(Vc + lb + (2 * s + 0) * FRAG);
      bf16x8 b1 = *(const bf16x8*)(Vc + lb + (2 * s + 1) * FRAG);
      o0 = MFMA32(b0, pb[s], o0);
      o1 = MFMA32(b1, pb[s], o1);
    }
    __builtin_amdgcn_s_setprio(0);
  }

  // ---- KV-split combine: 4 -> 2 -> 1 (exact: partials additive) ----
  __syncthreads();                            // last computes done
  float* cb = (float*)&KV[0][0][0][0];        // scratch; rounds use <70KB
  const int cbase = wq * 64 + ln;             // 0..255

  // round 1: groups 2,3 publish; groups 0,1 absorb
  if (g >= 2) {
    const int base = ((g - 2) * 256 + cbase) * 33;
#pragma unroll
    for (int i = 0; i < 16; ++i) { cb[base + i] = o0[i]; cb[base + 16 + i] = o1[i]; }
    cb[base + 32] = l_run;
  }
  __syncthreads();
  if (g < 2) {
    const int base = (g * 256 + cbase) * 33;
#pragma unroll
    for (int i = 0; i < 16; ++i) { o0[i] += cb[base + i]; o1[i] += cb[base + 16 + i]; }
    l_run += cb[base + 32];
  }
  __syncthreads();
  // round 2: group 1 publishes; group 0 absorbs
  if (g == 1) {
    const int base = cbase * 33;
#pragma unroll
    for (int i = 0; i < 16; ++i) { cb[base + i] = o0[i]; cb[base + 16 + i] = o1[i]; }
    cb[base + 32] = l_run;
  }
  __syncthreads();
  if (g == 0) {
    const int base = cbase * 33;
#pragma unroll
    for (int i = 0; i < 16; ++i) { o0[i] += cb[base + i]; o1[i] += cb[base + 16 + i]; }
    l_run += cb[base + 32];

    // ---- epilogue: l across h-halves, normalize, store ----
    const float lt  = l_run + __shfl_xor(l_run, 32);
    const float inv = 1.f / lt;
    const int bb = bh >> 2, hd = bh & 3;
    float* op = out + ((size_t)(bb * S_LEN + q)) * D_MODEL + hd * DH;
#pragma unroll
    for (int gg = 0; gg < 4; ++gg) {
      float4 v0, v1;
      v0.x = o0[4 * gg + 0] * inv;  v0.y = o0[4 * gg + 1] * inv;
      v0.z = o0[4 * gg + 2] * inv;  v0.w = o0[4 * gg + 3] * inv;
      *(float4*)(op + 8 * gg + 4 * h) = v0;
      v1.x = o1[4 * gg + 0] * inv;  v1.y = o1[4 * gg + 1] * inv;
      v1.z = o1[4 * gg + 2] * inv;  v1.w = o1[4 * gg + 3] * inv;
      *(float4*)(op + 32 + 8 * gg + 4 * h) = v1;
    }
  }
}

// ---------------------------------------------------------------------------
extern "C" void kernel_launch(void* const* d_in, const int* in_sizes, int n_in,
                              void* d_out, int out_size, void* d_ws, size_t ws_size,
                              hipStream_t stream) {
  const float* x  = (const float*)d_in[0];
  const float* Wq = (const float*)d_in[1];
  const float* bq = (const float*)d_in[2];
  const float* Wk = (const float*)d_in[3];
  const float* bk = (const float*)d_in[4];
  const float* Wv = (const float*)d_in[5];
  const float* bv = (const float*)d_in[6];
  float* out = (float*)d_out;

  const size_t per = (size_t)2 * NH * S_LEN * DH;       // 2M bf16 elems each
  if (ws_size < 3 * per * sizeof(unsigned short)) return;
  unsigned short* Qh = (unsigned short*)d_ws;
  unsigned short* Kh = Qh + per;
  unsigned short* Vt = Kh + per;
  unsigned short* Wb = (unsigned short*)d_out;   // scratch; attn overwrites out

  prep<<<96, 256, 0, stream>>>(Wq, Wk, Wv, Wb);
  qkv_proj<<<1024, 256, 0, stream>>>(x, Wb, bq, bk, bv, Qh, Kh, Vt);
  attn<<<256, 1024, 0, stream>>>(Qh, Kh, Vt, out);
}